// Round 2
// baseline (118.000 us; speedup 1.0000x reference)
//
#include <hip/hip_runtime.h>
#include <math.h>

#define BATCH 8
#define NSLOT 256
#define DDIM  256
#define HID   128
#define NREL  8

// ---------------------------------------------------------------------------
// Kernel 1: per-slot projection.  P[row][0:128] = slots_row @ W1[:256] + b1
//                                 P[row][128:256] = slots_row @ W1[256:]
// 256 blocks x 256 threads, 8 rows/block. W1 staged through LDS in 32-k
// chunks (bulk float4 loads); slot values are wave-uniform -> s_load.
// ---------------------------------------------------------------------------
__global__ __launch_bounds__(256, 4) void proj_kernel(
    const float* __restrict__ slots, const float* __restrict__ W1,
    const float* __restrict__ b1, float* __restrict__ P) {
  __shared__ float Wl[32 * 256];  // 32 KB: Wl[kk][c]; c<128 -> W1 top half, else bottom

  const int tid  = threadIdx.x;
  const int row0 = blockIdx.x * 8;
  const float* srow = slots + (size_t)row0 * DDIM;

  const float bias = (tid < HID) ? b1[tid] : 0.0f;
  float acc[8];
#pragma unroll
  for (int r = 0; r < 8; ++r) acc[r] = bias;

  for (int k0 = 0; k0 < DDIM; k0 += 32) {
    // Stage Wl[kk][c] = (c<128) ? W1[k0+kk][c] : W1[256+k0+kk][c-128]
    // 32x256 floats = 2048 float4 = 8 per thread, coalesced.
#pragma unroll
    for (int t = 0; t < 8; ++t) {
      const int idx4 = tid + t * 256;
      const int kk = idx4 >> 6;          // 0..31
      const int c  = (idx4 & 63) * 4;    // 0..252
      const float* g = (c < HID)
          ? (W1 + (size_t)(k0 + kk) * HID + c)
          : (W1 + (size_t)(DDIM + k0 + kk) * HID + (c - HID));
      *(float4*)&Wl[kk * 256 + c] = *(const float4*)g;
    }
    __syncthreads();

#pragma unroll 4
    for (int kk = 0; kk < 32; ++kk) {
      const float w = Wl[kk * 256 + tid];  // lane-consecutive, 2-way alias = free
#pragma unroll
      for (int r = 0; r < 8; ++r) {
        acc[r] = fmaf(srow[r * DDIM + k0 + kk], w, acc[r]);  // uniform -> s_load
      }
    }
    __syncthreads();
  }

#pragma unroll
  for (int r = 0; r < 8; ++r) {
    P[(size_t)(row0 + r) * 256 + tid] = acc[r];
  }
}

// ---------------------------------------------------------------------------
// Kernel 2: pair grid.
// out[b,i,j,r] = sigmoid( sum_k relu(P[b,i,k] + P[b,j,128+k]) * W2[k,r] + b2[r] )
// Grid (16,16,8) = 2048 blocks (8 blocks/CU), 256 threads, 1 pair/thread.
// Pi/Pj tiles in LDS as float4 rows with stride 33 (=132 floats: Pi 4-row
// groups land on disjoint bank quads; Pj 16 rows alias max 2-way = free).
// W2/b2 uniform -> SGPR operands into v_fmac.
// ---------------------------------------------------------------------------
__global__ __launch_bounds__(256, 8) void pair_kernel(
    const float* __restrict__ P, const float* __restrict__ W2,
    const float* __restrict__ b2, float* __restrict__ out) {
  __shared__ float4 Pi4[16 * 33];
  __shared__ float4 Pj4[16 * 33];

  const int tid = threadIdx.x;
  const int j0  = blockIdx.x * 16;
  const int i0  = blockIdx.y * 16;
  const int b   = blockIdx.z;
  const float* Pb = P + (size_t)b * NSLOT * 256;

  // Stage: 16 rows x 32 float4 each side; 1024 float4 total, 4/thread.
  {
    const int r  = tid >> 5;         // 0..7
    const int c4 = tid & 31;         // 0..31
    Pi4[(r)     * 33 + c4] = *(const float4*)&Pb[(size_t)(i0 + r)     * 256 + c4 * 4];
    Pi4[(r + 8) * 33 + c4] = *(const float4*)&Pb[(size_t)(i0 + r + 8) * 256 + c4 * 4];
    Pj4[(r)     * 33 + c4] = *(const float4*)&Pb[(size_t)(j0 + r)     * 256 + 128 + c4 * 4];
    Pj4[(r + 8) * 33 + c4] = *(const float4*)&Pb[(size_t)(j0 + r + 8) * 256 + 128 + c4 * 4];
  }
  __syncthreads();

  const int tj = tid & 15;
  const int ti = tid >> 4;

  float acc[NREL];
#pragma unroll
  for (int r = 0; r < NREL; ++r) acc[r] = 0.0f;

#pragma unroll 2
  for (int kc = 0; kc < 32; ++kc) {
    const float4 a = Pi4[ti * 33 + kc];
    const float4 c = Pj4[tj * 33 + kc];
    float h[4];
    h[0] = fmaxf(a.x + c.x, 0.0f);
    h[1] = fmaxf(a.y + c.y, 0.0f);
    h[2] = fmaxf(a.z + c.z, 0.0f);
    h[3] = fmaxf(a.w + c.w, 0.0f);
#pragma unroll
    for (int kk = 0; kk < 4; ++kk) {
      const int k = kc * 4 + kk;
#pragma unroll
      for (int r = 0; r < NREL; ++r) {
        acc[r] = fmaf(h[kk], W2[k * NREL + r], acc[r]);  // W2 uniform -> s_load
      }
    }
  }

  // Epilogue: bias, sigmoid, two coalesced float4 stores.
  float res[8] __attribute__((aligned(16)));
#pragma unroll
  for (int r = 0; r < NREL; ++r) {
    const float x = acc[r] + b2[r];
    res[r] = 1.0f / (1.0f + __expf(-x));
  }
  float* o = out + (((size_t)b * NSLOT + (i0 + ti)) * NSLOT + (j0 + tj)) * NREL;
  *(float4*)&o[0] = *(const float4*)&res[0];
  *(float4*)&o[4] = *(const float4*)&res[4];
}

extern "C" void kernel_launch(void* const* d_in, const int* in_sizes, int n_in,
                              void* d_out, int out_size, void* d_ws, size_t ws_size,
                              hipStream_t stream) {
  const float* slots = (const float*)d_in[0];  // [8,256,256]
  const float* W1    = (const float*)d_in[1];  // [512,128]
  const float* b1    = (const float*)d_in[2];  // [128]
  const float* W2    = (const float*)d_in[3];  // [128,8]
  const float* b2    = (const float*)d_in[4];  // [8]
  float* out = (float*)d_out;                  // [8,256,256,8]
  float* P   = (float*)d_ws;                   // [2048][256] fp32 = 2 MB scratch

  proj_kernel<<<dim3(BATCH * NSLOT / 8), 256, 0, stream>>>(slots, W1, b1, P);
  pair_kernel<<<dim3(NSLOT / 16, NSLOT / 16, BATCH), 256, 0, stream>>>(P, W2, b2, out);
}

// Round 3
// 95.887 us; speedup vs baseline: 1.2306x; 1.2306x over previous
//
#include <hip/hip_runtime.h>
#include <math.h>

#define BATCH 8
#define NSLOT 256
#define DDIM  256
#define HID   128
#define NREL  8

// ---------------------------------------------------------------------------
// Kernel 1 (v3): per-slot projection. P[row][0:128] = slots_row @ W1[:256] + b1
//                                     P[row][128:256] = slots_row @ W1[256:]
// 512 blocks x 256 threads, 4 rows/block, full K, NO LDS / NO barriers.
// Lane = output col. W1 loads: 16-deep preload -> 16 outstanding vmem loads.
// slots row values are wave-uniform -> compiler emits batched s_load_dwordx8.
// 2 blocks/CU (2 waves/SIMD) + deep unroll hides L2/scalar latency.
// ---------------------------------------------------------------------------
__global__ __launch_bounds__(256, 2) void proj_kernel(
    const float* __restrict__ slots, const float* __restrict__ W1,
    const float* __restrict__ b1, float* __restrict__ P) {
  const int tid  = threadIdx.x;
  const int row0 = blockIdx.x * 4;
  const int c    = tid;  // 0..255 (wave-uniform branch: waves 0-1 vs 2-3)
  const bool isP1 = (c < HID);
  const float* Wcol = isP1 ? (W1 + c) : (W1 + DDIM * HID + (c - HID));
  const float bias = isP1 ? b1[c] : 0.0f;

  float acc[4];
#pragma unroll
  for (int r = 0; r < 4; ++r) acc[r] = bias;

  const float* srow = slots + (size_t)row0 * DDIM;

  for (int k = 0; k < DDIM; k += 16) {
    // 16 independent coalesced loads in flight (vmcnt-batched).
    float w[16];
#pragma unroll
    for (int u = 0; u < 16; ++u) w[u] = Wcol[(size_t)(k + u) * HID];
#pragma unroll
    for (int u = 0; u < 16; ++u) {
#pragma unroll
      for (int r = 0; r < 4; ++r) {
        acc[r] = fmaf(srow[r * DDIM + k + u], w[u], acc[r]);  // uniform -> s_load
      }
    }
  }

#pragma unroll
  for (int r = 0; r < 4; ++r) {
    P[(size_t)(row0 + r) * 256 + c] = acc[r];
  }
}

// ---------------------------------------------------------------------------
// Kernel 2 (v2, UNCHANGED this round to isolate the proj change and surface
// pair's counters in the top-5):
// out[b,i,j,r] = sigmoid( sum_k relu(P[b,i,k] + P[b,j,128+k]) * W2[k,r] + b2[r] )
// Grid (16,16,8) = 2048 blocks (8 blocks/CU), 256 threads, 1 pair/thread.
// ---------------------------------------------------------------------------
__global__ __launch_bounds__(256, 8) void pair_kernel(
    const float* __restrict__ P, const float* __restrict__ W2,
    const float* __restrict__ b2, float* __restrict__ out) {
  __shared__ float4 Pi4[16 * 33];
  __shared__ float4 Pj4[16 * 33];

  const int tid = threadIdx.x;
  const int j0  = blockIdx.x * 16;
  const int i0  = blockIdx.y * 16;
  const int b   = blockIdx.z;
  const float* Pb = P + (size_t)b * NSLOT * 256;

  // Stage: 16 rows x 32 float4 each side; 1024 float4 total, 4/thread.
  {
    const int r  = tid >> 5;         // 0..7
    const int c4 = tid & 31;         // 0..31
    Pi4[(r)     * 33 + c4] = *(const float4*)&Pb[(size_t)(i0 + r)     * 256 + c4 * 4];
    Pi4[(r + 8) * 33 + c4] = *(const float4*)&Pb[(size_t)(i0 + r + 8) * 256 + c4 * 4];
    Pj4[(r)     * 33 + c4] = *(const float4*)&Pb[(size_t)(j0 + r)     * 256 + 128 + c4 * 4];
    Pj4[(r + 8) * 33 + c4] = *(const float4*)&Pb[(size_t)(j0 + r + 8) * 256 + 128 + c4 * 4];
  }
  __syncthreads();

  const int tj = tid & 15;
  const int ti = tid >> 4;

  float acc[NREL];
#pragma unroll
  for (int r = 0; r < NREL; ++r) acc[r] = 0.0f;

#pragma unroll 2
  for (int kc = 0; kc < 32; ++kc) {
    const float4 a = Pi4[ti * 33 + kc];
    const float4 c = Pj4[tj * 33 + kc];
    float h[4];
    h[0] = fmaxf(a.x + c.x, 0.0f);
    h[1] = fmaxf(a.y + c.y, 0.0f);
    h[2] = fmaxf(a.z + c.z, 0.0f);
    h[3] = fmaxf(a.w + c.w, 0.0f);
#pragma unroll
    for (int kk = 0; kk < 4; ++kk) {
      const int k = kc * 4 + kk;
#pragma unroll
      for (int r = 0; r < NREL; ++r) {
        acc[r] = fmaf(h[kk], W2[k * NREL + r], acc[r]);  // W2 uniform -> s_load
      }
    }
  }

  // Epilogue: bias, sigmoid, two coalesced float4 stores.
  float res[8] __attribute__((aligned(16)));
#pragma unroll
  for (int r = 0; r < NREL; ++r) {
    const float x = acc[r] + b2[r];
    res[r] = 1.0f / (1.0f + __expf(-x));
  }
  float* o = out + (((size_t)b * NSLOT + (i0 + ti)) * NSLOT + (j0 + tj)) * NREL;
  *(float4*)&o[0] = *(const float4*)&res[0];
  *(float4*)&o[4] = *(const float4*)&res[4];
}

extern "C" void kernel_launch(void* const* d_in, const int* in_sizes, int n_in,
                              void* d_out, int out_size, void* d_ws, size_t ws_size,
                              hipStream_t stream) {
  const float* slots = (const float*)d_in[0];  // [8,256,256]
  const float* W1    = (const float*)d_in[1];  // [512,128]
  const float* b1    = (const float*)d_in[2];  // [128]
  const float* W2    = (const float*)d_in[3];  // [128,8]
  const float* b2    = (const float*)d_in[4];  // [8]
  float* out = (float*)d_out;                  // [8,256,256,8]
  float* P   = (float*)d_ws;                   // [2048][256] fp32 = 2 MB scratch

  proj_kernel<<<dim3(BATCH * NSLOT / 4), 256, 0, stream>>>(slots, W1, b1, P);
  pair_kernel<<<dim3(NSLOT / 16, NSLOT / 16, BATCH), 256, 0, stream>>>(P, W2, b2, out);
}

// Round 5
// 86.515 us; speedup vs baseline: 1.3639x; 1.1083x over previous
//
#include <hip/hip_runtime.h>
#include <hip/hip_fp16.h>
#include <math.h>

#define BATCH 8
#define NSLOT 256
#define DDIM  256
#define HID   128
#define NREL  8

typedef _Float16 half8 __attribute__((ext_vector_type(8)));
typedef float float4v __attribute__((ext_vector_type(4)));

union U8 {
  uint32_t u[4];
  _Float16 f[8];
  half8 v;
  float4 f4;
};

// ---------------------------------------------------------------------------
// Kernel 1 (v4): projection, fp32 math, f16 output.
// P[row][0:128] = slots_row @ W1[:256] + b1 ; P[row][128:256] = slots_row @ W1[256:]
// 1024 blocks x 256 threads, 2 rows/block (4 blocks/CU -> 4 waves/SIMD).
// W1 re-read per block: 268 MB L2 traffic ~= 8 us floor; latency hidden by
// occupancy + 16-deep load batch. srow operands wave-uniform -> s_load.
// ---------------------------------------------------------------------------
__global__ __launch_bounds__(256, 4) void proj_kernel(
    const float* __restrict__ slots, const float* __restrict__ W1,
    const float* __restrict__ b1, _Float16* __restrict__ P) {
  const int tid  = threadIdx.x;
  const int row0 = blockIdx.x * 2;
  const int c    = tid;
  const bool isP1 = (c < HID);
  const float* Wcol = isP1 ? (W1 + c) : (W1 + DDIM * HID + (c - HID));
  const float bias = isP1 ? b1[c] : 0.0f;

  float acc0 = bias, acc1 = bias;
  const float* srow = slots + (size_t)row0 * DDIM;

  for (int k = 0; k < DDIM; k += 16) {
    float w[16];
#pragma unroll
    for (int u = 0; u < 16; ++u) w[u] = Wcol[(size_t)(k + u) * HID];
#pragma unroll
    for (int u = 0; u < 16; ++u) {
      acc0 = fmaf(srow[k + u], w[u], acc0);          // uniform -> s_load
      acc1 = fmaf(srow[DDIM + k + u], w[u], acc1);   // uniform -> s_load
    }
  }

  P[(size_t)(row0)     * 256 + c] = (_Float16)acc0;
  P[(size_t)(row0 + 1) * 256 + c] = (_Float16)acc1;
}

// ---------------------------------------------------------------------------
// Kernel 2 (v3b): pair grid via f16 MFMA.
// out[b,i,j,r] = sigmoid( sum_k relu(Pi[i,k]+Pj[j,k]) * W2[k,r] + b2[r] )
// Block = 16 i's x 64 j's, 4 waves; wave w owns j-strip of 16. Per wave:
//  - Pj A-side fragments (16 j x 128 k f16) loaded ONCE into 16 VGPRs
//  - W2 B-fragments (cols 8..15 zero) in 16 VGPRs
//  - loop over 16 i's: 4x [Pi LDS broadcast b128 + pk_add/pk_max h-gen +
//    mfma_f32_16x16x32_f16] -> sigmoid epilogue. No barriers in the loop.
// h-gen uses native _Float16 ext-vectors (v_pk_add_f16 / v_pk_max_f16) —
// HIP __half2 intrinsic overloads are broken for this on ROCm 7.2.
// MFMA mappings (m89-verified, dtype-independent):
//  A[m][k]: m=lane&15, k=(lane>>4)*8+u ; B[k][n]: n=lane&15, k=(lane>>4)*8+u
//  D: col(n)=lane&15, row(m)=(lane>>4)*4+reg
// ---------------------------------------------------------------------------
__global__ __launch_bounds__(256) void pair_kernel(
    const _Float16* __restrict__ P, const float* __restrict__ W2,
    const float* __restrict__ b2, float* __restrict__ out) {
  __shared__ uint32_t PiL[16 * 68];  // 16 rows x 128 f16, stride 68 dwords (pad)

  const int tid  = threadIdx.x;
  const int w    = tid >> 6;
  const int lane = tid & 63;
  const int n    = lane & 15;   // MFMA n / m column within 16-group
  const int kg   = lane >> 4;   // MFMA k-group (0..3)

  const int b   = blockIdx.z;
  const int i0  = blockIdx.y * 16;
  const int j0  = blockIdx.x * 64 + w * 16;
  const _Float16* Pb = P + (size_t)b * NSLOT * 256;

  // Stage Pi (i-half of P, bias already folded) into LDS: 16 rows x 128 f16.
  {
    const int r  = tid >> 4;        // 0..15
    const int ch = tid & 15;        // 16B chunk
    const float4 t = *(const float4*)(Pb + (size_t)(i0 + r) * 256 + ch * 8);
    *(float4*)&PiL[r * 68 + ch * 4] = t;
  }
  __syncthreads();

  // W2 B-fragments: w2f[kq].f[u] = W2[kq*32 + kg*8 + u][n], zero for n>=8.
  U8 w2f[4];
#pragma unroll
  for (int kq = 0; kq < 4; ++kq) {
#pragma unroll
    for (int u = 0; u < 8; ++u) {
      const int k = kq * 32 + kg * 8 + u;
      w2f[kq].f[u] = (n < 8) ? (_Float16)W2[k * NREL + n] : (_Float16)0.0f;
    }
  }
  const float b2v = (n < 8) ? b2[n] : 0.0f;

  // Pj A-fragment pieces: pj[kq] = 8 f16 of Pj[j0+n][128 + kq*32 + kg*8 ..].
  U8 pj[4];
#pragma unroll
  for (int kq = 0; kq < 4; ++kq) {
    pj[kq].f4 = *(const float4*)(Pb + (size_t)(j0 + n) * 256 + HID + kq * 32 + kg * 8);
  }

  for (int i = 0; i < 16; ++i) {
    float4v acc = {0.0f, 0.0f, 0.0f, 0.0f};
#pragma unroll
    for (int kq = 0; kq < 4; ++kq) {
      U8 pi;
      pi.f4 = *(const float4*)&PiL[i * 68 + kq * 16 + kg * 4];  // broadcast, conflict-free
      U8 h;
      h.v = __builtin_elementwise_max(pj[kq].v + pi.v, (half8)(_Float16)0.0f);
      acc = __builtin_amdgcn_mfma_f32_16x16x32_f16(h.v, w2f[kq].v, acc, 0, 0, 0);
    }
    // Epilogue: lane holds D[row=kg*4+reg][col=n]; valid rels are n<8.
    if (n < 8) {
      float* obase = out + (((size_t)b * NSLOT + (i0 + i)) * NSLOT + j0) * NREL + n;
#pragma unroll
      for (int reg = 0; reg < 4; ++reg) {
        const int jrow = kg * 4 + reg;
        const float x = acc[reg] + b2v;
        obase[jrow * NREL] = __builtin_amdgcn_rcpf(1.0f + __expf(-x));
      }
    }
  }
}

extern "C" void kernel_launch(void* const* d_in, const int* in_sizes, int n_in,
                              void* d_out, int out_size, void* d_ws, size_t ws_size,
                              hipStream_t stream) {
  const float* slots = (const float*)d_in[0];  // [8,256,256]
  const float* W1    = (const float*)d_in[1];  // [512,128]
  const float* b1    = (const float*)d_in[2];  // [128]
  const float* W2    = (const float*)d_in[3];  // [128,8]
  const float* b2    = (const float*)d_in[4];  // [8]
  float* out    = (float*)d_out;               // [8,256,256,8]
  _Float16* P   = (_Float16*)d_ws;             // [2048][256] f16 = 1 MB scratch

  proj_kernel<<<dim3(BATCH * NSLOT / 2), 256, 0, stream>>>(slots, W1, b1, P);
  pair_kernel<<<dim3(NSLOT / 64, NSLOT / 16, BATCH), 256, 0, stream>>>(P, W2, b2, out);
}